// Round 8
// baseline (225.627 us; speedup 1.0000x reference)
//
#include <hip/hip_runtime.h>
#include <stdint.h>

typedef _Float16 half8 __attribute__((ext_vector_type(8)));
typedef _Float16 f16x4 __attribute__((ext_vector_type(4)));
typedef _Float16 f16x2 __attribute__((ext_vector_type(2)));
typedef float floatx4 __attribute__((ext_vector_type(4)));
typedef float fvec4 __attribute__((ext_vector_type(4)));

struct WPtrs { const float *wc, *wn, *wp, *we; };

#if __has_builtin(__builtin_amdgcn_fdot2)
static __device__ inline float dot2(f16x2 a, f16x2 b, float c) {
  return __builtin_amdgcn_fdot2(a, b, c, false);
}
#else
static __device__ inline float dot2(f16x2 a, f16x2 b, float c) {
  return c + (float)a[0] * (float)b[0] + (float)a[1] * (float)b[1];
}
#endif

// ---------------------------------------------------------------------------
// Fused prep kernel: grid = [norm blocks | part blocks | 4 weight blocks]
//  - norm: x rows -> unit fp16 xhat
//  - part: per-node fp16 partial score from p/e terms
//          (weights fp16-packed in LDS: [e0..e7 | p0,p1,p2,0 | pad4], stride 16;
//           2 nodes/thread; v_dot2_f32_f16 inner product)
//  - weights: Wc+Wn normalized+scaled into psi (fp16, MFMA B layout)
// ---------------------------------------------------------------------------
struct PrepArgs {
  const float* x; _Float16* xhat; int N; int nb_norm;
  const float* p[4]; const float* e[4]; _Float16* part[4];
  int nd[4];
  int pb[5];                 // cumulative part-block offsets (after nb_norm)
  WPtrs w[4]; _Float16* psi;
};

template <int D>
__device__ inline void part_one(const PrepArgs& a, int g, int lblk, int tid,
                                _Float16* wl) {
  const float* __restrict__ p  = a.p[g];
  const float* __restrict__ e  = a.e[g];
  _Float16* __restrict__ part  = a.part[g];
  int nd = a.nd[g];

  // ---- stage fp16 normalized+scaled weights into LDS ----
  if (tid < 16 * D) {  // tid = k*D+s
    const float* sp = a.w[g].wp + tid * 3;
    float a0 = sp[0], a1 = sp[1], a2 = sp[2];
    float n1 = sqrtf(a0 * a0 + a1 * a1 + a2 * a2);
    float s1 = n1 > 0.f ? 0.25f / (D * n1) : 0.f;
    const float* se = a.w[g].we + tid * 8;
    float b0 = se[0], b1 = se[1], b2 = se[2], b3 = se[3];
    float b4 = se[4], b5 = se[5], b6 = se[6], b7 = se[7];
    float n2 = sqrtf(b0 * b0 + b1 * b1 + b2 * b2 + b3 * b3 +
                     b4 * b4 + b5 * b5 + b6 * b6 + b7 * b7);
    float s2 = n2 > 0.f ? 0.25f / (D * n2) : 0.f;
    _Float16* w = wl + tid * 16;
    w[0] = (_Float16)(b0 * s2); w[1] = (_Float16)(b1 * s2);
    w[2] = (_Float16)(b2 * s2); w[3] = (_Float16)(b3 * s2);
    w[4] = (_Float16)(b4 * s2); w[5] = (_Float16)(b5 * s2);
    w[6] = (_Float16)(b6 * s2); w[7] = (_Float16)(b7 * s2);
    w[8] = (_Float16)(a0 * s1); w[9] = (_Float16)(a1 * s1);
    w[10] = (_Float16)(a2 * s1); w[11] = (_Float16)0.f;
  }
  __syncthreads();

  int node0 = lblk * 512 + tid;
  if (node0 >= nd) return;
  int node1 = node0 + 256;
  int node1c = node1 < nd ? node1 : nd - 1;

  // ---- load + normalize feats for both nodes (fp16 pairs) ----
  f16x2 ph2[2][D][2], eh2[2][D][4];
  int nods[2] = {node0, node1c};
#pragma unroll
  for (int n = 0; n < 2; ++n) {
#pragma unroll
    for (int s = 0; s < D; ++s) {
      const float* pp = p + ((size_t)nods[n] * D + s) * 3;
      float a0 = pp[0], a1 = pp[1], a2 = pp[2];
      float n1 = sqrtf(a0 * a0 + a1 * a1 + a2 * a2);
      float r1 = n1 > 0.f ? 1.f / n1 : 0.f;
      ph2[n][s][0] = f16x2{(_Float16)(a0 * r1), (_Float16)(a1 * r1)};
      ph2[n][s][1] = f16x2{(_Float16)(a2 * r1), (_Float16)0.f};

      const fvec4* ee = reinterpret_cast<const fvec4*>(e + ((size_t)nods[n] * D + s) * 8);
      fvec4 e0 = ee[0], e1 = ee[1];
      float n2 = sqrtf(e0[0] * e0[0] + e0[1] * e0[1] + e0[2] * e0[2] + e0[3] * e0[3] +
                       e1[0] * e1[0] + e1[1] * e1[1] + e1[2] * e1[2] + e1[3] * e1[3]);
      float r2 = n2 > 0.f ? 1.f / n2 : 0.f;
      eh2[n][s][0] = f16x2{(_Float16)(e0[0] * r2), (_Float16)(e0[1] * r2)};
      eh2[n][s][1] = f16x2{(_Float16)(e0[2] * r2), (_Float16)(e0[3] * r2)};
      eh2[n][s][2] = f16x2{(_Float16)(e1[0] * r2), (_Float16)(e1[1] * r2)};
      eh2[n][s][3] = f16x2{(_Float16)(e1[2] * r2), (_Float16)(e1[3] * r2)};
    }
  }

  // ---- 16 partial scores per node via dot2 ----
  half8 h0a, h1a, h0b, h1b;
#pragma unroll
  for (int k = 0; k < 16; ++k) {
    float t0 = 0.f, t1 = 0.f;
#pragma unroll
    for (int s = 0; s < D; ++s) {
      const _Float16* w = wl + (k * D + s) * 16;
      half8 we = *reinterpret_cast<const half8*>(w);
      f16x4 wp = *reinterpret_cast<const f16x4*>(w + 8);
      f16x2 we0 = __builtin_shufflevector(we, we, 0, 1);
      f16x2 we1 = __builtin_shufflevector(we, we, 2, 3);
      f16x2 we2 = __builtin_shufflevector(we, we, 4, 5);
      f16x2 we3 = __builtin_shufflevector(we, we, 6, 7);
      f16x2 wp0 = __builtin_shufflevector(wp, wp, 0, 1);
      f16x2 wp1 = __builtin_shufflevector(wp, wp, 2, 3);
      t0 = dot2(eh2[0][s][0], we0, t0); t1 = dot2(eh2[1][s][0], we0, t1);
      t0 = dot2(eh2[0][s][1], we1, t0); t1 = dot2(eh2[1][s][1], we1, t1);
      t0 = dot2(eh2[0][s][2], we2, t0); t1 = dot2(eh2[1][s][2], we2, t1);
      t0 = dot2(eh2[0][s][3], we3, t0); t1 = dot2(eh2[1][s][3], we3, t1);
      t0 = dot2(ph2[0][s][0], wp0, t0); t1 = dot2(ph2[1][s][0], wp0, t1);
      t0 = dot2(ph2[0][s][1], wp1, t0); t1 = dot2(ph2[1][s][1], wp1, t1);
    }
    if (k < 8) { h0a[k] = (_Float16)t0; h0b[k] = (_Float16)t1; }
    else       { h1a[k - 8] = (_Float16)t0; h1b[k - 8] = (_Float16)t1; }
  }
  _Float16* dst0 = part + (size_t)node0 * 16;
  *reinterpret_cast<half8*>(dst0)     = h0a;
  *reinterpret_cast<half8*>(dst0 + 8) = h1a;
  if (node1 < nd) {
    _Float16* dst1 = part + (size_t)node1 * 16;
    *reinterpret_cast<half8*>(dst1)     = h0b;
    *reinterpret_cast<half8*>(dst1 + 8) = h1b;
  }
}

__global__ __launch_bounds__(256) void k_prep(PrepArgs a) {
  __shared__ _Float16 wl[64 * 16];
  int bid = blockIdx.x, tid = threadIdx.x;

  if (bid < a.nb_norm) {
    // ---- normalize x rows: 4 lanes per row ----
    int row = bid * 64 + (tid >> 2);
    int q   = tid & 3;
    if (row >= a.N) return;
    const fvec4* xr = reinterpret_cast<const fvec4*>(a.x + (size_t)row * 32 + q * 8);
    fvec4 va = xr[0];
    fvec4 vb = xr[1];
    float ss = va[0] * va[0] + va[1] * va[1] + va[2] * va[2] + va[3] * va[3] +
               vb[0] * vb[0] + vb[1] * vb[1] + vb[2] * vb[2] + vb[3] * vb[3];
    ss += __shfl_xor(ss, 1);
    ss += __shfl_xor(ss, 2);
    float rn = ss > 0.f ? rsqrtf(ss) : 0.f;
    half8 h;
    h[0] = (_Float16)(va[0] * rn); h[1] = (_Float16)(va[1] * rn);
    h[2] = (_Float16)(va[2] * rn); h[3] = (_Float16)(va[3] * rn);
    h[4] = (_Float16)(vb[0] * rn); h[5] = (_Float16)(vb[1] * rn);
    h[6] = (_Float16)(vb[2] * rn); h[7] = (_Float16)(vb[3] * rn);
    *reinterpret_cast<half8*>(a.xhat + (size_t)row * 32 + q * 8) = h;
    return;
  }

  int b2 = bid - a.nb_norm;
  if (b2 < a.pb[4]) {
    if      (b2 < a.pb[1]) part_one<1>(a, 0, b2,           tid, wl);
    else if (b2 < a.pb[2]) part_one<2>(a, 1, b2 - a.pb[1], tid, wl);
    else if (b2 < a.pb[3]) part_one<3>(a, 2, b2 - a.pb[2], tid, wl);
    else                   part_one<4>(a, 3, b2 - a.pb[3], tid, wl);
    return;
  }

  // ---- pack Wc + Wn into psi: row k = [wc(32) | wn_s(32)*d], fp16 ----
  int g = b2 - a.pb[4];          // 0..3
  int d = g + 1;
  int KD = 32 * (1 + d);
  _Float16* pg = a.psi + (size_t)g * (16 * 160);

  int k     = tid & 15;
  int piece = tid >> 4;
  if (piece > d) return;
  const float* src;
  float scale;
  if (piece == 0) { src = a.w[g].wc + k * 32;                          scale = 0.25f; }
  else            { src = a.w[g].wn + (size_t)(k * d + piece - 1) * 32; scale = 0.25f / d; }
  float ss = 0.f;
  for (int j = 0; j < 32; ++j) ss += src[j] * src[j];
  float n  = sqrtf(ss);
  float sc = n > 0.f ? scale / n : 0.f;
  _Float16* dst = pg + k * KD + 32 * piece;
  for (int j = 0; j < 32; ++j) dst[j] = (_Float16)(src[j] * sc);
}

// ---------------------------------------------------------------------------
// Fused main kernel: gathered MFMA GEMM (x terms only), acc seeded with the
// fp16 p/e partial. NCH chunks per wave for memory-level parallelism.
// MFMA 16x16x32 f16:  A row = lane&15, B col = lane&15, k-chunk = lane>>4.
// C/D: col = lane&15, row = (lane>>4)*4 + reg  [verified layout].
// ---------------------------------------------------------------------------
struct MainArgs {
  const _Float16* xhat;
  const _Float16* part[4];
  const _Float16* psi;       // group g at psi + g*16*160, row stride KD(g)
  const int* sel[4];
  const int* nei[4];
  float* out;
  int nd[4];
  int blkOff[5];             // cumulative block offsets per group
};

template <int D, int NCH>
__device__ inline void main_one(const MainArgs& a, int g, int blk) {
  constexpr int NF = 1 + D;
  constexpr int KD = 32 * NF;

  const _Float16* xhat = a.xhat;
  const _Float16* part = a.part[g];
  const _Float16* psi  = a.psi + (size_t)g * (16 * 160);
  const int* sel = a.sel[g];
  const int* nei = a.nei[g];
  int nd = a.nd[g];

  int wave    = threadIdx.x >> 6;
  int lane    = threadIdx.x & 63;
  int nchunks = (nd + 15) >> 4;
  int chunk0  = (blk * 4 + wave) * NCH;
  if (chunk0 >= nchunks) return;
  int r = lane & 15;   // A row / B col / C col
  int c = lane >> 4;   // k-chunk

  // B fragments: loaded once, constant for the whole kernel.
  half8 bx[NF];
  {
    const _Float16* pb = psi + (size_t)r * KD + c * 8;
#pragma unroll
    for (int t = 0; t < NF; ++t)
      bx[t] = *reinterpret_cast<const half8*>(pb + 32 * t);
  }

  // ---- phase 1: indices for all NCH chunks (independent loads) ----
  int riA[NCH];
  int sidx[NCH];
  int gidx[NCH][D];
#pragma unroll
  for (int u = 0; u < NCH; ++u) {
    int chunk = chunk0 + u;
    int ri = (chunk < nchunks) ? (chunk * 16 + r) : 0;
    if (ri > nd - 1) ri = nd - 1;
    riA[u]  = ri;
    sidx[u] = sel[ri];
  }
#pragma unroll
  for (int u = 0; u < NCH; ++u)
#pragma unroll
    for (int s = 0; s < D; ++s)
      gidx[u][s] = nei[(size_t)riA[u] * D + s];

  // ---- phase 2: acc seed from partial + A-fragment gathers ----
  floatx4 acc[NCH];
#pragma unroll
  for (int u = 0; u < NCH; ++u) {
    int i0 = (chunk0 + u) << 4;
#pragma unroll
    for (int j = 0; j < 4; ++j) {
      int n = i0 + c * 4 + j;
      if (n > nd - 1) n = nd - 1;
      acc[u][j] = (float)part[(size_t)n * 16 + r];
    }
  }

  half8 af[NCH][NF];
#pragma unroll
  for (int u = 0; u < NCH; ++u) {
    af[u][0] = *reinterpret_cast<const half8*>(xhat + (size_t)sidx[u] * 32 + c * 8);
#pragma unroll
    for (int s = 0; s < D; ++s)
      af[u][1 + s] = *reinterpret_cast<const half8*>(xhat + (size_t)gidx[u][s] * 32 + c * 8);
  }

  // ---- phase 3: MFMAs ----
#pragma unroll
  for (int u = 0; u < NCH; ++u)
#pragma unroll
    for (int t = 0; t < NF; ++t)
      acc[u] = __builtin_amdgcn_mfma_f32_16x16x32_f16(af[u][t], bx[t], acc[u], 0, 0, 0);

  // ---- phase 4: writeback ----
#pragma unroll
  for (int u = 0; u < NCH; ++u) {
    int chunk = chunk0 + u;
    if (chunk >= nchunks) break;
    int i0 = chunk << 4;
#pragma unroll
    for (int j = 0; j < 4; ++j) {
      int n  = i0 + c * 4 + j;
      int so = __shfl(sidx[u], c * 4 + j);  // sel[i0 + c*4 + j]
      if (n < nd) {
        float* orow = a.out + (size_t)so * 64 + r;
#pragma unroll
        for (int q = 0; q < 4; ++q)
          orow[q * 16] = (q == D - 1) ? acc[u][j] : 0.f;
      }
    }
  }
}

__global__ __launch_bounds__(256) void k_main(MainArgs a) {
  int bid = blockIdx.x;
  if (bid < a.blkOff[1])      main_one<1, 6>(a, 0, bid);
  else if (bid < a.blkOff[2]) main_one<2, 5>(a, 1, bid - a.blkOff[1]);
  else if (bid < a.blkOff[3]) main_one<3, 4>(a, 2, bid - a.blkOff[2]);
  else                        main_one<4, 3>(a, 3, bid - a.blkOff[3]);
}

// ---------------------------------------------------------------------------
extern "C" void kernel_launch(void* const* d_in, const int* in_sizes, int n_in,
                              void* d_out, int out_size, void* d_ws, size_t ws_size,
                              hipStream_t stream) {
  const float* x = (const float*)d_in[0];
  int N = in_sizes[0] / 32;

  PrepArgs pa;
  MainArgs ma;
  pa.x = x; pa.N = N;
  int nd[4];
  for (int g = 0; g < 4; ++g) {
    int b = 1 + g * 8;
    ma.sel[g]  = (const int*)d_in[b + 0];
    ma.nei[g]  = (const int*)d_in[b + 1];
    pa.p[g]    = (const float*)d_in[b + 2];
    pa.e[g]    = (const float*)d_in[b + 3];
    pa.w[g].wc = (const float*)d_in[b + 4];
    pa.w[g].wn = (const float*)d_in[b + 5];
    pa.w[g].wp = (const float*)d_in[b + 6];
    pa.w[g].we = (const float*)d_in[b + 7];
    nd[g] = in_sizes[b];
    pa.nd[g] = nd[g];
    ma.nd[g] = nd[g];
  }
  ma.out = (float*)d_out;

  // workspace layout: xhat | part[4] | psi
  char* ws = (char*)d_ws;
  auto align256 = [](size_t o) { return (o + 255) & ~(size_t)255; };
  _Float16* xhat = (_Float16*)ws;
  size_t off = (size_t)N * 32 * 2;
  for (int g = 0; g < 4; ++g) {
    off = align256(off);
    pa.part[g] = (_Float16*)(ws + off);
    ma.part[g] = pa.part[g];
    off += (size_t)nd[g] * 16 * 2;
  }
  off = align256(off);
  _Float16* psi = (_Float16*)(ws + off);
  pa.psi = psi;
  ma.psi = psi;
  pa.xhat = xhat;
  ma.xhat = xhat;

  // prep grid: [norm | part | 4 weight blocks]
  pa.nb_norm = (N + 63) / 64;
  pa.pb[0] = 0;
  for (int g = 0; g < 4; ++g) pa.pb[g + 1] = pa.pb[g] + (nd[g] + 511) / 512;
  int prep_blocks = pa.nb_norm + pa.pb[4] + 4;

  // main grid: per-group block counts (4 waves/block, NCH chunks/wave)
  const int NCHg[4] = {6, 5, 4, 3};
  ma.blkOff[0] = 0;
  for (int g = 0; g < 4; ++g) {
    int ch = (nd[g] + 15) / 16;
    int perBlk = 4 * NCHg[g];
    ma.blkOff[g + 1] = ma.blkOff[g] + (ch + perBlk - 1) / perBlk;
  }

  k_prep<<<prep_blocks, 256, 0, stream>>>(pa);
  k_main<<<ma.blkOff[4], 256, 0, stream>>>(ma);
}

// Round 9
// 194.229 us; speedup vs baseline: 1.1617x; 1.1617x over previous
//
#include <hip/hip_runtime.h>
#include <stdint.h>

typedef _Float16 half8 __attribute__((ext_vector_type(8)));
typedef float floatx4 __attribute__((ext_vector_type(4)));
typedef float fvec4 __attribute__((ext_vector_type(4)));

struct WPtrs { const float *wc, *wn, *wp, *we; };

// ---------------------------------------------------------------------------
// Kernel 1: normalize x rows (N x 32 f32) -> xhat (N x 32 fp16). No LDS.
// ---------------------------------------------------------------------------
__global__ __launch_bounds__(256) void k_norm(const float* __restrict__ x,
                                              _Float16* __restrict__ xhat, int N) {
  int t = blockIdx.x * 256 + threadIdx.x;
  int row = t >> 2, q = t & 3;
  if (row >= N) return;
  const fvec4* xr = reinterpret_cast<const fvec4*>(x + (size_t)row * 32 + q * 8);
  fvec4 va = xr[0], vb = xr[1];
  float ss = va[0] * va[0] + va[1] * va[1] + va[2] * va[2] + va[3] * va[3] +
             vb[0] * vb[0] + vb[1] * vb[1] + vb[2] * vb[2] + vb[3] * vb[3];
  ss += __shfl_xor(ss, 1);
  ss += __shfl_xor(ss, 2);
  float rn = ss > 0.f ? rsqrtf(ss) : 0.f;
  half8 h;
  h[0] = (_Float16)(va[0] * rn); h[1] = (_Float16)(va[1] * rn);
  h[2] = (_Float16)(va[2] * rn); h[3] = (_Float16)(va[3] * rn);
  h[4] = (_Float16)(vb[0] * rn); h[5] = (_Float16)(vb[1] * rn);
  h[6] = (_Float16)(vb[2] * rn); h[7] = (_Float16)(vb[3] * rn);
  *reinterpret_cast<half8*>(xhat + (size_t)row * 32 + q * 8) = h;
}

// ---------------------------------------------------------------------------
// Kernel 2: part via MFMA.  grid = [part blocks (4 groups) | 4 psi blocks]
// Per part block: 256 threads each load+normalize ONE node's p/e slots into
// an LDS A row ([p0,p1,p2,0,e0..e7,0x4] per slot, row stride K32+8 halves);
// weights staged likewise into a 16-row B region. Each wave: 4 chunks of 16
// nodes -> 1-2 MFMA 16x16x32 -> part[node][k] fp16.
// MFMA: A row = lane&15, B col = lane&15, k-chunk = lane>>4.
// C/D: col = lane&15, row = (lane>>4)*4 + reg  [verified layout].
// ---------------------------------------------------------------------------
struct PartArgs {
  const float* p[4]; const float* e[4]; _Float16* part[4];
  int nd[4];
  int pb[5];                 // cumulative part-block offsets
  WPtrs w[4]; _Float16* psi;
};

template <int D>
__device__ inline void part_mfma(const PartArgs& a, int g, int lblk, int tid,
                                 _Float16* lds) {
  constexpr int K16 = 16 * D;
  constexpr int K32 = ((D + 1) / 2) * 32;
  constexpr int NM  = K32 / 32;
  constexpr int RS  = K32 + 8;     // +16B pad: row stride -> 2-way banks only

  const float* __restrict__ p = a.p[g];
  const float* __restrict__ e = a.e[g];
  _Float16* __restrict__ part = a.part[g];
  int nd = a.nd[g];

  _Float16* aLds = lds;
  _Float16* bLds = lds + 256 * RS;

  // ---- stage normalized+scaled weights into B region ----
  if (tid < 16 * D) {              // tid = k*D + s
    int k = tid / D, s = tid % D;
    const float* sp = a.w[g].wp + (size_t)tid * 3;
    float a0 = sp[0], a1 = sp[1], a2 = sp[2];
    float n1 = sqrtf(a0 * a0 + a1 * a1 + a2 * a2);
    float s1 = n1 > 0.f ? 0.25f / (D * n1) : 0.f;
    const float* se = a.w[g].we + (size_t)tid * 8;
    float b0 = se[0], b1 = se[1], b2 = se[2], b3 = se[3];
    float b4 = se[4], b5 = se[5], b6 = se[6], b7 = se[7];
    float n2 = sqrtf(b0 * b0 + b1 * b1 + b2 * b2 + b3 * b3 +
                     b4 * b4 + b5 * b5 + b6 * b6 + b7 * b7);
    float s2 = n2 > 0.f ? 0.25f / (D * n2) : 0.f;
    half8 h0, h1;
    h0[0] = (_Float16)(a0 * s1); h0[1] = (_Float16)(a1 * s1);
    h0[2] = (_Float16)(a2 * s1); h0[3] = (_Float16)0.f;
    h0[4] = (_Float16)(b0 * s2); h0[5] = (_Float16)(b1 * s2);
    h0[6] = (_Float16)(b2 * s2); h0[7] = (_Float16)(b3 * s2);
    h1[0] = (_Float16)(b4 * s2); h1[1] = (_Float16)(b5 * s2);
    h1[2] = (_Float16)(b6 * s2); h1[3] = (_Float16)(b7 * s2);
    h1[4] = (_Float16)0.f; h1[5] = (_Float16)0.f;
    h1[6] = (_Float16)0.f; h1[7] = (_Float16)0.f;
    _Float16* w = bLds + k * RS + s * 16;
    *reinterpret_cast<half8*>(w)     = h0;
    *reinterpret_cast<half8*>(w + 8) = h1;
  }
  if (K32 > K16 && tid < 16) {     // zero B pad [K16,K32)
    half8 z = {};
    _Float16* w = bLds + tid * RS + K16;
    *reinterpret_cast<half8*>(w)     = z;
    *reinterpret_cast<half8*>(w + 8) = z;
  }

  // ---- load + normalize own node -> A row ----
  int node = lblk * 256 + tid;
  int nc = node < nd ? node : nd - 1;
  _Float16* arow = aLds + tid * RS;
#pragma unroll
  for (int s = 0; s < D; ++s) {
    const float* pp = p + ((size_t)nc * D + s) * 3;
    float a0 = pp[0], a1 = pp[1], a2 = pp[2];
    float n1 = sqrtf(a0 * a0 + a1 * a1 + a2 * a2);
    float r1 = n1 > 0.f ? 1.f / n1 : 0.f;
    const fvec4* ee = reinterpret_cast<const fvec4*>(e + ((size_t)nc * D + s) * 8);
    fvec4 e0 = ee[0], e1 = ee[1];
    float n2 = sqrtf(e0[0] * e0[0] + e0[1] * e0[1] + e0[2] * e0[2] + e0[3] * e0[3] +
                     e1[0] * e1[0] + e1[1] * e1[1] + e1[2] * e1[2] + e1[3] * e1[3]);
    float r2 = n2 > 0.f ? 1.f / n2 : 0.f;
    half8 h0, h1;
    h0[0] = (_Float16)(a0 * r1); h0[1] = (_Float16)(a1 * r1);
    h0[2] = (_Float16)(a2 * r1); h0[3] = (_Float16)0.f;
    h0[4] = (_Float16)(e0[0] * r2); h0[5] = (_Float16)(e0[1] * r2);
    h0[6] = (_Float16)(e0[2] * r2); h0[7] = (_Float16)(e0[3] * r2);
    h1[0] = (_Float16)(e1[0] * r2); h1[1] = (_Float16)(e1[1] * r2);
    h1[2] = (_Float16)(e1[2] * r2); h1[3] = (_Float16)(e1[3] * r2);
    h1[4] = (_Float16)0.f; h1[5] = (_Float16)0.f;
    h1[6] = (_Float16)0.f; h1[7] = (_Float16)0.f;
    *reinterpret_cast<half8*>(arow + s * 16)     = h0;
    *reinterpret_cast<half8*>(arow + s * 16 + 8) = h1;
  }
  if (K32 > K16) {                 // zero A pad [K16,K32)
    half8 z = {};
    *reinterpret_cast<half8*>(arow + K16)     = z;
    *reinterpret_cast<half8*>(arow + K16 + 8) = z;
  }

  __syncthreads();

  int lane = tid & 63, wv = tid >> 6;
  int r = lane & 15, c = lane >> 4;

  half8 bf[NM];
#pragma unroll
  for (int m = 0; m < NM; ++m)
    bf[m] = *reinterpret_cast<const half8*>(bLds + r * RS + m * 32 + c * 8);

#pragma unroll
  for (int q = 0; q < 4; ++q) {
    half8 af[NM];
#pragma unroll
    for (int m = 0; m < NM; ++m)
      af[m] = *reinterpret_cast<const half8*>(aLds + (wv * 64 + q * 16 + r) * RS + m * 32 + c * 8);
    floatx4 acc = {0.f, 0.f, 0.f, 0.f};
#pragma unroll
    for (int m = 0; m < NM; ++m)
      acc = __builtin_amdgcn_mfma_f32_16x16x32_f16(af[m], bf[m], acc, 0, 0, 0);
    int nb = lblk * 256 + wv * 64 + q * 16;
#pragma unroll
    for (int j = 0; j < 4; ++j) {
      int ng = nb + c * 4 + j;
      if (ng < nd) part[(size_t)ng * 16 + r] = (_Float16)acc[j];
    }
  }
}

__global__ __launch_bounds__(256) void k_part(PartArgs a) {
  __shared__ _Float16 lds[256 * 72 + 16 * 72];
  int bid = blockIdx.x, tid = threadIdx.x;

  if (bid < a.pb[4]) {
    if      (bid < a.pb[1]) part_mfma<1>(a, 0, bid,           tid, lds);
    else if (bid < a.pb[2]) part_mfma<2>(a, 1, bid - a.pb[1], tid, lds);
    else if (bid < a.pb[3]) part_mfma<3>(a, 2, bid - a.pb[2], tid, lds);
    else                    part_mfma<4>(a, 3, bid - a.pb[3], tid, lds);
    return;
  }

  // ---- pack Wc + Wn into psi: row k = [wc(32) | wn_s(32)*d], fp16 ----
  int g = bid - a.pb[4];           // 0..3
  int d = g + 1;
  int KD = 32 * (1 + d);
  _Float16* pg = a.psi + (size_t)g * (16 * 160);

  int k     = tid & 15;
  int piece = tid >> 4;
  if (piece > d) return;
  const float* src;
  float scale;
  if (piece == 0) { src = a.w[g].wc + k * 32;                           scale = 0.25f; }
  else            { src = a.w[g].wn + (size_t)(k * d + piece - 1) * 32; scale = 0.25f / d; }
  float ss = 0.f;
  for (int j = 0; j < 32; ++j) ss += src[j] * src[j];
  float n  = sqrtf(ss);
  float sc = n > 0.f ? scale / n : 0.f;
  _Float16* dst = pg + k * KD + 32 * piece;
  for (int j = 0; j < 32; ++j) dst[j] = (_Float16)(src[j] * sc);
}

// ---------------------------------------------------------------------------
// Kernel 3 (main): gathered MFMA GEMM (x terms only), acc seeded with the
// fp16 p/e partial. NCH chunks per wave for memory-level parallelism.
// ---------------------------------------------------------------------------
struct MainArgs {
  const _Float16* xhat;
  const _Float16* part[4];
  const _Float16* psi;       // group g at psi + g*16*160, row stride KD(g)
  const int* sel[4];
  const int* nei[4];
  float* out;
  int nd[4];
  int blkOff[5];             // cumulative block offsets per group
};

template <int D, int NCH>
__device__ inline void main_one(const MainArgs& a, int g, int blk) {
  constexpr int NF = 1 + D;
  constexpr int KD = 32 * NF;

  const _Float16* xhat = a.xhat;
  const _Float16* part = a.part[g];
  const _Float16* psi  = a.psi + (size_t)g * (16 * 160);
  const int* sel = a.sel[g];
  const int* nei = a.nei[g];
  int nd = a.nd[g];

  int wave    = threadIdx.x >> 6;
  int lane    = threadIdx.x & 63;
  int nchunks = (nd + 15) >> 4;
  int chunk0  = (blk * 4 + wave) * NCH;
  if (chunk0 >= nchunks) return;
  int r = lane & 15;   // A row / B col / C col
  int c = lane >> 4;   // k-chunk

  half8 bx[NF];
  {
    const _Float16* pb = psi + (size_t)r * KD + c * 8;
#pragma unroll
    for (int t = 0; t < NF; ++t)
      bx[t] = *reinterpret_cast<const half8*>(pb + 32 * t);
  }

  // ---- phase 1: indices ----
  int riA[NCH];
  int sidx[NCH];
  int gidx[NCH][D];
#pragma unroll
  for (int u = 0; u < NCH; ++u) {
    int chunk = chunk0 + u;
    int ri = (chunk < nchunks) ? (chunk * 16 + r) : 0;
    if (ri > nd - 1) ri = nd - 1;
    riA[u]  = ri;
    sidx[u] = sel[ri];
  }
#pragma unroll
  for (int u = 0; u < NCH; ++u)
#pragma unroll
    for (int s = 0; s < D; ++s)
      gidx[u][s] = nei[(size_t)riA[u] * D + s];

  // ---- phase 2: acc seed from partial + A-fragment gathers ----
  floatx4 acc[NCH];
#pragma unroll
  for (int u = 0; u < NCH; ++u) {
    int i0 = (chunk0 + u) << 4;
#pragma unroll
    for (int j = 0; j < 4; ++j) {
      int n = i0 + c * 4 + j;
      if (n > nd - 1) n = nd - 1;
      acc[u][j] = (float)part[(size_t)n * 16 + r];
    }
  }

  half8 af[NCH][NF];
#pragma unroll
  for (int u = 0; u < NCH; ++u) {
    af[u][0] = *reinterpret_cast<const half8*>(xhat + (size_t)sidx[u] * 32 + c * 8);
#pragma unroll
    for (int s = 0; s < D; ++s)
      af[u][1 + s] = *reinterpret_cast<const half8*>(xhat + (size_t)gidx[u][s] * 32 + c * 8);
  }

  // ---- phase 3: MFMAs ----
#pragma unroll
  for (int u = 0; u < NCH; ++u)
#pragma unroll
    for (int t = 0; t < NF; ++t)
      acc[u] = __builtin_amdgcn_mfma_f32_16x16x32_f16(af[u][t], bx[t], acc[u], 0, 0, 0);

  // ---- phase 4: writeback ----
#pragma unroll
  for (int u = 0; u < NCH; ++u) {
    int chunk = chunk0 + u;
    if (chunk >= nchunks) break;
    int i0 = chunk << 4;
#pragma unroll
    for (int j = 0; j < 4; ++j) {
      int n  = i0 + c * 4 + j;
      int so = __shfl(sidx[u], c * 4 + j);  // sel[i0 + c*4 + j]
      if (n < nd) {
        float* orow = a.out + (size_t)so * 64 + r;
#pragma unroll
        for (int q = 0; q < 4; ++q)
          orow[q * 16] = (q == D - 1) ? acc[u][j] : 0.f;
      }
    }
  }
}

__global__ __launch_bounds__(256) void k_main(MainArgs a) {
  int bid = blockIdx.x;
  if (bid < a.blkOff[1])      main_one<1, 6>(a, 0, bid);
  else if (bid < a.blkOff[2]) main_one<2, 5>(a, 1, bid - a.blkOff[1]);
  else if (bid < a.blkOff[3]) main_one<3, 4>(a, 2, bid - a.blkOff[2]);
  else                        main_one<4, 3>(a, 3, bid - a.blkOff[3]);
}

// ---------------------------------------------------------------------------
extern "C" void kernel_launch(void* const* d_in, const int* in_sizes, int n_in,
                              void* d_out, int out_size, void* d_ws, size_t ws_size,
                              hipStream_t stream) {
  const float* x = (const float*)d_in[0];
  int N = in_sizes[0] / 32;

  PartArgs pra;
  MainArgs ma;
  int nd[4];
  for (int g = 0; g < 4; ++g) {
    int b = 1 + g * 8;
    ma.sel[g]   = (const int*)d_in[b + 0];
    ma.nei[g]   = (const int*)d_in[b + 1];
    pra.p[g]    = (const float*)d_in[b + 2];
    pra.e[g]    = (const float*)d_in[b + 3];
    pra.w[g].wc = (const float*)d_in[b + 4];
    pra.w[g].wn = (const float*)d_in[b + 5];
    pra.w[g].wp = (const float*)d_in[b + 6];
    pra.w[g].we = (const float*)d_in[b + 7];
    nd[g] = in_sizes[b];
    pra.nd[g] = nd[g];
    ma.nd[g]  = nd[g];
  }
  ma.out = (float*)d_out;

  // workspace layout: xhat | part[4] | psi
  char* ws = (char*)d_ws;
  auto align256 = [](size_t o) { return (o + 255) & ~(size_t)255; };
  _Float16* xhat = (_Float16*)ws;
  size_t off = (size_t)N * 32 * 2;
  for (int g = 0; g < 4; ++g) {
    off = align256(off);
    pra.part[g] = (_Float16*)(ws + off);
    ma.part[g]  = pra.part[g];
    off += (size_t)nd[g] * 16 * 2;
  }
  off = align256(off);
  _Float16* psi = (_Float16*)(ws + off);
  pra.psi = psi;
  ma.psi  = psi;
  ma.xhat = xhat;

  // part grid: per-group 256-node blocks + 4 psi blocks
  pra.pb[0] = 0;
  for (int g = 0; g < 4; ++g) pra.pb[g + 1] = pra.pb[g] + (nd[g] + 255) / 256;

  // main grid: per-group block counts (4 waves/block, NCH chunks/wave)
  const int NCHg[4] = {6, 5, 4, 3};
  ma.blkOff[0] = 0;
  for (int g = 0; g < 4; ++g) {
    int ch = (nd[g] + 15) / 16;
    int perBlk = 4 * NCHg[g];
    ma.blkOff[g + 1] = ma.blkOff[g] + (ch + perBlk - 1) / perBlk;
  }

  k_norm<<<(N * 4 + 255) / 256, 256, 0, stream>>>(x, xhat, N);
  k_part<<<pra.pb[4] + 4, 256, 0, stream>>>(pra);
  k_main<<<ma.blkOff[4], 256, 0, stream>>>(ma);
}

// Round 10
// 191.268 us; speedup vs baseline: 1.1796x; 1.0155x over previous
//
#include <hip/hip_runtime.h>
#include <stdint.h>

typedef _Float16 half8 __attribute__((ext_vector_type(8)));
typedef float floatx4 __attribute__((ext_vector_type(4)));
typedef float fvec4 __attribute__((ext_vector_type(4)));

struct WPtrs { const float *wc, *wn, *wp, *we; };

// ---------------------------------------------------------------------------
// Fused prep kernel: grid = [norm blocks | part blocks (4 groups) | 4 psi]
//  - norm: x rows -> unit fp16 xhat (no LDS, pure streaming)
//  - part: per-node fp16 partial score from p/e via MFMA.
//      * A: each lane stages ITS node's packed slots into the wave's private
//        64-row LDS region -> no __syncthreads (wave-synchronous LDS).
//      * B: computed per-lane in registers from global weights (L2-resident):
//        lane (r,c), sub-K m needs slot s = 2m + (c>>1) of row k=r.
//      * 4 chunks of 16 nodes per wave -> NM MFMAs each -> part fp16.
//  - psi: Wc+Wn normalized+scaled (fp16, MFMA B layout) for k_main.
// MFMA 16x16x32 f16:  A row = lane&15, B col = lane&15, k-chunk = lane>>4.
// C/D: col = lane&15, row = (lane>>4)*4 + reg  [verified layout].
// ---------------------------------------------------------------------------
struct PrepArgs {
  const float* x; _Float16* xhat; int N; int nb_norm;
  const float* p[4]; const float* e[4]; _Float16* part[4];
  int nd[4];
  int pb[5];                 // cumulative part-block offsets (after nb_norm)
  WPtrs w[4]; _Float16* psi;
};

template <int D>
__device__ inline void part_mfma(const PrepArgs& a, int g, int lblk, int tid,
                                 _Float16* lds) {
  constexpr int K16 = 16 * D;
  constexpr int K32 = ((D + 1) / 2) * 32;   // K rounded to MFMA depth
  constexpr int NM  = K32 / 32;             // MFMAs per chunk
  constexpr int RS  = K32 + 8;              // row stride (halves): bank spread

  const float* __restrict__ p = a.p[g];
  const float* __restrict__ e = a.e[g];
  _Float16* __restrict__ part = a.part[g];
  int nd = a.nd[g];

  int lane = tid & 63, wv = tid >> 6;
  int r = lane & 15, c = lane >> 4;

  // ---- A staging: this lane's node -> wave-private LDS row ----
  int node = lblk * 256 + tid;
  int nc = node < nd ? node : nd - 1;
  _Float16* arow = lds + (size_t)tid * RS;
#pragma unroll
  for (int s = 0; s < D; ++s) {
    const float* pp = p + ((size_t)nc * D + s) * 3;
    float a0 = pp[0], a1 = pp[1], a2 = pp[2];
    float n1 = sqrtf(a0 * a0 + a1 * a1 + a2 * a2);
    float r1 = n1 > 0.f ? 1.f / n1 : 0.f;
    const fvec4* ee = reinterpret_cast<const fvec4*>(e + ((size_t)nc * D + s) * 8);
    fvec4 e0 = ee[0], e1 = ee[1];
    float n2 = sqrtf(e0[0] * e0[0] + e0[1] * e0[1] + e0[2] * e0[2] + e0[3] * e0[3] +
                     e1[0] * e1[0] + e1[1] * e1[1] + e1[2] * e1[2] + e1[3] * e1[3]);
    float r2 = n2 > 0.f ? 1.f / n2 : 0.f;
    half8 h0, h1;
    h0[0] = (_Float16)(a0 * r1); h0[1] = (_Float16)(a1 * r1);
    h0[2] = (_Float16)(a2 * r1); h0[3] = (_Float16)0.f;
    h0[4] = (_Float16)(e0[0] * r2); h0[5] = (_Float16)(e0[1] * r2);
    h0[6] = (_Float16)(e0[2] * r2); h0[7] = (_Float16)(e0[3] * r2);
    h1[0] = (_Float16)(e1[0] * r2); h1[1] = (_Float16)(e1[1] * r2);
    h1[2] = (_Float16)(e1[2] * r2); h1[3] = (_Float16)(e1[3] * r2);
    h1[4] = (_Float16)0.f; h1[5] = (_Float16)0.f;
    h1[6] = (_Float16)0.f; h1[7] = (_Float16)0.f;
    *reinterpret_cast<half8*>(arow + s * 16)     = h0;
    *reinterpret_cast<half8*>(arow + s * 16 + 8) = h1;
  }
  if (K32 > K16) {                 // zero A pad (B is zero there too, but
    half8 z = {};                  // avoid NaN*0 from stale LDS)
    *reinterpret_cast<half8*>(arow + K16)     = z;
    *reinterpret_cast<half8*>(arow + K16 + 8) = z;
  }

  // ---- B fragments in registers, straight from global weights ----
  half8 bf[NM];
#pragma unroll
  for (int m = 0; m < NM; ++m) {
    int s = 2 * m + (c >> 1);
    if (s < D) {
      const float* sp = a.w[g].wp + ((size_t)r * D + s) * 3;
      float a0 = sp[0], a1 = sp[1], a2 = sp[2];
      float n1 = sqrtf(a0 * a0 + a1 * a1 + a2 * a2);
      float s1 = n1 > 0.f ? 0.25f / (D * n1) : 0.f;
      const float* se = a.w[g].we + ((size_t)r * D + s) * 8;
      float b0 = se[0], b1 = se[1], b2 = se[2], b3 = se[3];
      float b4 = se[4], b5 = se[5], b6 = se[6], b7 = se[7];
      float n2 = sqrtf(b0 * b0 + b1 * b1 + b2 * b2 + b3 * b3 +
                       b4 * b4 + b5 * b5 + b6 * b6 + b7 * b7);
      float s2 = n2 > 0.f ? 0.25f / (D * n2) : 0.f;
      half8 h;
      if ((c & 1) == 0) {
        h[0] = (_Float16)(a0 * s1); h[1] = (_Float16)(a1 * s1);
        h[2] = (_Float16)(a2 * s1); h[3] = (_Float16)0.f;
        h[4] = (_Float16)(b0 * s2); h[5] = (_Float16)(b1 * s2);
        h[6] = (_Float16)(b2 * s2); h[7] = (_Float16)(b3 * s2);
      } else {
        h[0] = (_Float16)(b4 * s2); h[1] = (_Float16)(b5 * s2);
        h[2] = (_Float16)(b6 * s2); h[3] = (_Float16)(b7 * s2);
        h[4] = (_Float16)0.f; h[5] = (_Float16)0.f;
        h[6] = (_Float16)0.f; h[7] = (_Float16)0.f;
      }
      bf[m] = h;
    } else {
      bf[m] = half8{};             // K-pad region
    }
  }

  __builtin_amdgcn_wave_barrier();   // keep LDS writes before reads (sched)

  // ---- per-wave: 4 chunks of 16 nodes -> MFMA -> part ----
#pragma unroll
  for (int q = 0; q < 4; ++q) {
    half8 af[NM];
#pragma unroll
    for (int m = 0; m < NM; ++m)
      af[m] = *reinterpret_cast<const half8*>(
          lds + (size_t)(wv * 64 + q * 16 + r) * RS + m * 32 + c * 8);
    floatx4 acc = {0.f, 0.f, 0.f, 0.f};
#pragma unroll
    for (int m = 0; m < NM; ++m)
      acc = __builtin_amdgcn_mfma_f32_16x16x32_f16(af[m], bf[m], acc, 0, 0, 0);
    int nb = lblk * 256 + wv * 64 + q * 16;
#pragma unroll
    for (int j = 0; j < 4; ++j) {
      int ng = nb + c * 4 + j;
      if (ng < nd) part[(size_t)ng * 16 + r] = (_Float16)acc[j];
    }
  }
}

__global__ __launch_bounds__(256) void k_prep(PrepArgs a) {
  __shared__ _Float16 lds[256 * 72];   // 36 KB: max over D of 256*RS(D)
  int bid = blockIdx.x, tid = threadIdx.x;

  if (bid < a.nb_norm) {
    // ---- normalize x rows: 4 lanes per row ----
    int row = bid * 64 + (tid >> 2);
    int q   = tid & 3;
    if (row >= a.N) return;
    const fvec4* xr = reinterpret_cast<const fvec4*>(a.x + (size_t)row * 32 + q * 8);
    fvec4 va = xr[0], vb = xr[1];
    float ss = va[0] * va[0] + va[1] * va[1] + va[2] * va[2] + va[3] * va[3] +
               vb[0] * vb[0] + vb[1] * vb[1] + vb[2] * vb[2] + vb[3] * vb[3];
    ss += __shfl_xor(ss, 1);
    ss += __shfl_xor(ss, 2);
    float rn = ss > 0.f ? rsqrtf(ss) : 0.f;
    half8 h;
    h[0] = (_Float16)(va[0] * rn); h[1] = (_Float16)(va[1] * rn);
    h[2] = (_Float16)(va[2] * rn); h[3] = (_Float16)(va[3] * rn);
    h[4] = (_Float16)(vb[0] * rn); h[5] = (_Float16)(vb[1] * rn);
    h[6] = (_Float16)(vb[2] * rn); h[7] = (_Float16)(vb[3] * rn);
    *reinterpret_cast<half8*>(a.xhat + (size_t)row * 32 + q * 8) = h;
    return;
  }

  int b2 = bid - a.nb_norm;
  if (b2 < a.pb[4]) {
    if      (b2 < a.pb[1]) part_mfma<1>(a, 0, b2,           tid, lds);
    else if (b2 < a.pb[2]) part_mfma<2>(a, 1, b2 - a.pb[1], tid, lds);
    else if (b2 < a.pb[3]) part_mfma<3>(a, 2, b2 - a.pb[2], tid, lds);
    else                   part_mfma<4>(a, 3, b2 - a.pb[3], tid, lds);
    return;
  }

  // ---- pack Wc + Wn into psi: row k = [wc(32) | wn_s(32)*d], fp16 ----
  int g = b2 - a.pb[4];            // 0..3
  int d = g + 1;
  int KD = 32 * (1 + d);
  _Float16* pg = a.psi + (size_t)g * (16 * 160);

  int k     = tid & 15;
  int piece = tid >> 4;
  if (piece > d) return;
  const float* src;
  float scale;
  if (piece == 0) { src = a.w[g].wc + k * 32;                           scale = 0.25f; }
  else            { src = a.w[g].wn + (size_t)(k * d + piece - 1) * 32; scale = 0.25f / d; }
  float ss = 0.f;
  for (int j = 0; j < 32; ++j) ss += src[j] * src[j];
  float n  = sqrtf(ss);
  float sc = n > 0.f ? scale / n : 0.f;
  _Float16* dst = pg + k * KD + 32 * piece;
  for (int j = 0; j < 32; ++j) dst[j] = (_Float16)(src[j] * sc);
}

// ---------------------------------------------------------------------------
// Main kernel: gathered MFMA GEMM (x terms only), acc seeded with the fp16
// p/e partial. NCH chunks per wave for memory-level parallelism.
// ---------------------------------------------------------------------------
struct MainArgs {
  const _Float16* xhat;
  const _Float16* part[4];
  const _Float16* psi;       // group g at psi + g*16*160, row stride KD(g)
  const int* sel[4];
  const int* nei[4];
  float* out;
  int nd[4];
  int blkOff[5];             // cumulative block offsets per group
};

template <int D, int NCH>
__device__ inline void main_one(const MainArgs& a, int g, int blk) {
  constexpr int NF = 1 + D;
  constexpr int KD = 32 * NF;

  const _Float16* xhat = a.xhat;
  const _Float16* part = a.part[g];
  const _Float16* psi  = a.psi + (size_t)g * (16 * 160);
  const int* sel = a.sel[g];
  const int* nei = a.nei[g];
  int nd = a.nd[g];

  int wave    = threadIdx.x >> 6;
  int lane    = threadIdx.x & 63;
  int nchunks = (nd + 15) >> 4;
  int chunk0  = (blk * 4 + wave) * NCH;
  if (chunk0 >= nchunks) return;
  int r = lane & 15;   // A row / B col / C col
  int c = lane >> 4;   // k-chunk

  half8 bx[NF];
  {
    const _Float16* pb = psi + (size_t)r * KD + c * 8;
#pragma unroll
    for (int t = 0; t < NF; ++t)
      bx[t] = *reinterpret_cast<const half8*>(pb + 32 * t);
  }

  // ---- phase 1: indices ----
  int riA[NCH];
  int sidx[NCH];
  int gidx[NCH][D];
#pragma unroll
  for (int u = 0; u < NCH; ++u) {
    int chunk = chunk0 + u;
    int ri = (chunk < nchunks) ? (chunk * 16 + r) : 0;
    if (ri > nd - 1) ri = nd - 1;
    riA[u]  = ri;
    sidx[u] = sel[ri];
  }
#pragma unroll
  for (int u = 0; u < NCH; ++u)
#pragma unroll
    for (int s = 0; s < D; ++s)
      gidx[u][s] = nei[(size_t)riA[u] * D + s];

  // ---- phase 2: acc seed from partial + A-fragment gathers ----
  floatx4 acc[NCH];
#pragma unroll
  for (int u = 0; u < NCH; ++u) {
    int i0 = (chunk0 + u) << 4;
#pragma unroll
    for (int j = 0; j < 4; ++j) {
      int n = i0 + c * 4 + j;
      if (n > nd - 1) n = nd - 1;
      acc[u][j] = (float)part[(size_t)n * 16 + r];
    }
  }

  half8 af[NCH][NF];
#pragma unroll
  for (int u = 0; u < NCH; ++u) {
    af[u][0] = *reinterpret_cast<const half8*>(xhat + (size_t)sidx[u] * 32 + c * 8);
#pragma unroll
    for (int s = 0; s < D; ++s)
      af[u][1 + s] = *reinterpret_cast<const half8*>(xhat + (size_t)gidx[u][s] * 32 + c * 8);
  }

  // ---- phase 3: MFMAs ----
#pragma unroll
  for (int u = 0; u < NCH; ++u)
#pragma unroll
    for (int t = 0; t < NF; ++t)
      acc[u] = __builtin_amdgcn_mfma_f32_16x16x32_f16(af[u][t], bx[t], acc[u], 0, 0, 0);

  // ---- phase 4: writeback ----
#pragma unroll
  for (int u = 0; u < NCH; ++u) {
    int chunk = chunk0 + u;
    if (chunk >= nchunks) break;
    int i0 = chunk << 4;
#pragma unroll
    for (int j = 0; j < 4; ++j) {
      int n  = i0 + c * 4 + j;
      int so = __shfl(sidx[u], c * 4 + j);  // sel[i0 + c*4 + j]
      if (n < nd) {
        float* orow = a.out + (size_t)so * 64 + r;
#pragma unroll
        for (int q = 0; q < 4; ++q)
          orow[q * 16] = (q == D - 1) ? acc[u][j] : 0.f;
      }
    }
  }
}

__global__ __launch_bounds__(256) void k_main(MainArgs a) {
  int bid = blockIdx.x;
  if (bid < a.blkOff[1])      main_one<1, 6>(a, 0, bid);
  else if (bid < a.blkOff[2]) main_one<2, 5>(a, 1, bid - a.blkOff[1]);
  else if (bid < a.blkOff[3]) main_one<3, 4>(a, 2, bid - a.blkOff[2]);
  else                        main_one<4, 3>(a, 3, bid - a.blkOff[3]);
}

// ---------------------------------------------------------------------------
extern "C" void kernel_launch(void* const* d_in, const int* in_sizes, int n_in,
                              void* d_out, int out_size, void* d_ws, size_t ws_size,
                              hipStream_t stream) {
  const float* x = (const float*)d_in[0];
  int N = in_sizes[0] / 32;

  PrepArgs pa;
  MainArgs ma;
  pa.x = x; pa.N = N;
  int nd[4];
  for (int g = 0; g < 4; ++g) {
    int b = 1 + g * 8;
    ma.sel[g]  = (const int*)d_in[b + 0];
    ma.nei[g]  = (const int*)d_in[b + 1];
    pa.p[g]    = (const float*)d_in[b + 2];
    pa.e[g]    = (const float*)d_in[b + 3];
    pa.w[g].wc = (const float*)d_in[b + 4];
    pa.w[g].wn = (const float*)d_in[b + 5];
    pa.w[g].wp = (const float*)d_in[b + 6];
    pa.w[g].we = (const float*)d_in[b + 7];
    nd[g] = in_sizes[b];
    pa.nd[g] = nd[g];
    ma.nd[g] = nd[g];
  }
  ma.out = (float*)d_out;

  // workspace layout: xhat | part[4] | psi
  char* ws = (char*)d_ws;
  auto align256 = [](size_t o) { return (o + 255) & ~(size_t)255; };
  _Float16* xhat = (_Float16*)ws;
  size_t off = (size_t)N * 32 * 2;
  for (int g = 0; g < 4; ++g) {
    off = align256(off);
    pa.part[g] = (_Float16*)(ws + off);
    ma.part[g] = pa.part[g];
    off += (size_t)nd[g] * 16 * 2;
  }
  off = align256(off);
  _Float16* psi = (_Float16*)(ws + off);
  pa.psi = psi;
  ma.psi = psi;
  ma.xhat = xhat;
  pa.xhat = xhat;

  // prep grid: [norm | part | 4 psi blocks]
  pa.nb_norm = (N + 63) / 64;
  pa.pb[0] = 0;
  for (int g = 0; g < 4; ++g) pa.pb[g + 1] = pa.pb[g] + (nd[g] + 255) / 256;
  int prep_blocks = pa.nb_norm + pa.pb[4] + 4;

  // main grid: per-group block counts (4 waves/block, NCH chunks/wave)
  const int NCHg[4] = {6, 5, 4, 3};
  ma.blkOff[0] = 0;
  for (int g = 0; g < 4; ++g) {
    int ch = (nd[g] + 15) / 16;
    int perBlk = 4 * NCHg[g];
    ma.blkOff[g + 1] = ma.blkOff[g] + (ch + perBlk - 1) / perBlk;
  }

  k_prep<<<prep_blocks, 256, 0, stream>>>(pa);
  k_main<<<ma.blkOff[4], 256, 0, stream>>>(ma);
}